// Round 3
// baseline (514.086 us; speedup 1.0000x reference)
//
#include <hip/hip_runtime.h>
#include <math.h>

#define BT 8192      // B*T
#define NDIM 512     // INPUT_DIM
#define NFREQ 257
#define DDIM 128     // VQ_DIM
#define NEMBED 8192

typedef _Float16 half8 __attribute__((ext_vector_type(8)));
typedef _Float16 half2v __attribute__((ext_vector_type(2)));
typedef float f32x4 __attribute__((ext_vector_type(4)));

#define SCALE_DN 2.44140625e-4f   // 2^-12

// ---------------- K table: K_s[delta] = sum_{f: rm[f]==s} w_f cos(2*pi*f*delta/512) ----
__global__ __launch_bounds__(512) void build_K_kernel(const int* __restrict__ rm,
                                                      float* __restrict__ Kmat) {
    __shared__ float ctab[512];
    __shared__ int rms[NFREQ];
    int t = threadIdx.x;
    ctab[t] = cospif((float)t * (1.0f / 256.0f));   // cos(2*pi*t/512)
    if (t < NFREQ) rms[t] = rm[t];
    __syncthreads();
    float acc0 = 0.f, acc1 = 0.f, acc2 = 0.f, acc3 = 0.f;
    for (int f = 0; f < NFREQ; ++f) {
        float w = (f == 0 || f == 256) ? 1.0f : 2.0f;
        float c = w * ctab[(f * t) & 511];
        int s = rms[f];
        acc0 += (s == 0) ? c : 0.0f;
        acc1 += (s == 1) ? c : 0.0f;
        acc2 += (s == 2) ? c : 0.0f;
        acc3 += (s == 3) ? c : 0.0f;
    }
    const float sc = 1.0f / 512.0f;
    Kmat[0 * 512 + t] = acc0 * sc;
    Kmat[1 * 512 + t] = acc1 * sc;
    Kmat[2 * 512 + t] = acc2 * sc;
    Kmat[3 * 512 + t] = acc3 * sc;
}

// ---------------- W[n][s*128+d] = sum_p proj[p][d] * K_s[(p-n)&511] --------------------
// register-window version: per 16-p block, 31 uniform Ks reads feed 256 fmaf
__global__ __launch_bounds__(128) void build_W_kernel(const float* __restrict__ proj,
                                                      const float* __restrict__ Kmat,
                                                      float* __restrict__ W) {
    int nt = blockIdx.x, s = blockIdx.y, d = threadIdx.x;
    int n0 = nt * 16;
    __shared__ float Ks[512];
    for (int i = d; i < 512; i += 128) Ks[i] = Kmat[s * 512 + i];
    __syncthreads();
    float acc[16] = {};
    for (int p16 = 0; p16 < 512; p16 += 16) {
        float wv[31];
#pragma unroll
        for (int j2 = 0; j2 < 31; ++j2) wv[j2] = Ks[(p16 - n0 + j2 - 15) & 511];
#pragma unroll
        for (int j = 0; j < 16; ++j) {
            float xp = proj[(p16 + j) * DDIM + d];
#pragma unroll
            for (int i = 0; i < 16; ++i)
                acc[i] = fmaf(xp, wv[15 + j - i], acc[i]);
        }
    }
#pragma unroll
    for (int i = 0; i < 16; ++i) W[(n0 + i) * 512 + s * DDIM + d] = acc[i];
}

// ---------------- Wt_hi/lo[c][k] = f16split(256 * W[k][c]) ------------------------------
// x256 pre-scale avoids f16 denormals; feat row-norm cancels it.
__global__ __launch_bounds__(256) void wsplit_kernel(const float* __restrict__ W,
                                                     _Float16* __restrict__ Wth,
                                                     _Float16* __restrict__ Wtl) {
    __shared__ float tile[64][65];
    int t = threadIdx.x;
    int k0 = blockIdx.x * 64, c0 = blockIdx.y * 64;
    int kr = t >> 2, cq = (t & 3) * 16;
#pragma unroll
    for (int j = 0; j < 16; j += 4) {
        float4 v = *(const float4*)(W + (k0 + kr) * 512 + c0 + cq + j);
        tile[kr][cq + j + 0] = v.x;
        tile[kr][cq + j + 1] = v.y;
        tile[kr][cq + j + 2] = v.z;
        tile[kr][cq + j + 3] = v.w;
    }
    __syncthreads();
    int c = t >> 2, kq = (t & 3) * 16;
    half8 ph0, ph1, pl0, pl1;
#pragma unroll
    for (int j = 0; j < 8; ++j) {
        float f = tile[kq + j][c] * 256.0f;
        _Float16 h = (_Float16)f;
        ph0[j] = h;
        pl0[j] = (_Float16)((f - (float)h) * 4096.0f);
    }
#pragma unroll
    for (int j = 0; j < 8; ++j) {
        float f = tile[kq + 8 + j][c] * 256.0f;
        _Float16 h = (_Float16)f;
        ph1[j] = h;
        pl1[j] = (_Float16)((f - (float)h) * 4096.0f);
    }
    _Float16* dh = Wth + (size_t)(c0 + c) * 512 + k0 + kq;
    _Float16* dl = Wtl + (size_t)(c0 + c) * 512 + k0 + kq;
    *(half8*)(dh) = ph0; *(half8*)(dh + 8) = ph1;
    *(half8*)(dl) = pl0; *(half8*)(dl + 8) = pl1;
}

// ---------------- codebook: normalize + f16 hi/lo split, written in DMA/LDS-image order -
// ws layout: [tile=code>>4][row=code&15][slot cp][8 f16], slot cp holds chunk cp^(row&7)
__global__ __launch_bounds__(256) void cbsplit_kernel(const float* __restrict__ cb,
                                                      _Float16* __restrict__ chi,
                                                      _Float16* __restrict__ clo) {
    int code = blockIdx.x * 4 + (threadIdx.x >> 6);
    int l = threadIdx.x & 63;
    float2 v = ((const float2*)(cb + (size_t)code * DDIM))[l];
    float ss = fmaf(v.x, v.x, v.y * v.y);
#pragma unroll
    for (int m = 32; m; m >>= 1) ss += __shfl_xor(ss, m);
    float r = 1.0f / sqrtf(ss);
    float a = v.x * r, b = v.y * r;
    _Float16 ha = (_Float16)a, hb = (_Float16)b;
    half2v hv = {ha, hb};
    half2v lv = {(_Float16)((a - (float)ha) * 4096.0f), (_Float16)((b - (float)hb) * 4096.0f)};
    int row = code & 15, tile = code >> 4;
    int cp = (l >> 2) ^ (row & 7);
    size_t base = (size_t)tile * 2048 + row * 128 + cp * 8 + (l & 3) * 2;
    *(half2v*)(chi + base) = hv;
    *(half2v*)(clo + base) = lv;
}

// ---------------- fused feat: feat = x @ W (f16x3 MFMA), row-normalize, split hi/lo -----
// grid (128 bt-tiles of 64, 4 splits); block 256 = 4 waves x 16 rows; K=512 in 16 steps
__global__ __launch_bounds__(256) void fused_feat(const float* __restrict__ x,
                                                  const _Float16* __restrict__ Wth,
                                                  const _Float16* __restrict__ Wtl,
                                                  _Float16* __restrict__ fhi,
                                                  _Float16* __restrict__ flo) {
    __shared__ __align__(16) char smem[59392];
    float* xs = (float*)smem;                       // [2][64][36] f32
    _Float16* Wh = (_Float16*)(smem + 18432);       // [2][128][40] f16
    _Float16* Wl = (_Float16*)(smem + 38912);       // [2][128][40] f16

    int t = threadIdx.x;
    int w = t >> 6, lr = t & 15, lg = (t >> 4) & 3;
    int row0 = blockIdx.x * 64;
    int sIdx = blockIdx.y;

    // staging maps
    int xr_r = t >> 2, xr_c = (t & 3) * 8;          // x: 64 rows x 32 k
    int wcol = t >> 1, wh_h = t & 1;                // W: 128 cols x 32 k
    const float* xsrc = x + (size_t)(row0 + xr_r) * NDIM + xr_c;
    const _Float16* whsrc = Wth + (size_t)(sIdx * 128 + wcol) * 512 + wh_h * 16;
    const _Float16* wlsrc = Wtl + (size_t)(sIdx * 128 + wcol) * 512 + wh_h * 16;

    f32x4 c0[8], c1[8];
#pragma unroll
    for (int i = 0; i < 8; ++i) { c0[i] = (f32x4){0.f,0.f,0.f,0.f}; c1[i] = c0[i]; }

    // prologue: stage step 0 into buf 0
    {
        float4 a0 = *(const float4*)(xsrc);
        float4 a1 = *(const float4*)(xsrc + 4);
        *(float4*)&xs[xr_r * 36 + xr_c] = a0;
        *(float4*)&xs[xr_r * 36 + xr_c + 4] = a1;
        half8 h0 = *(const half8*)(whsrc);
        half8 h1 = *(const half8*)(whsrc + 8);
        half8 l0 = *(const half8*)(wlsrc);
        half8 l1 = *(const half8*)(wlsrc + 8);
        *(half8*)&Wh[wcol * 40 + wh_h * 16] = h0;
        *(half8*)&Wh[wcol * 40 + wh_h * 16 + 8] = h1;
        *(half8*)&Wl[wcol * 40 + wh_h * 16] = l0;
        *(half8*)&Wl[wcol * 40 + wh_h * 16 + 8] = l1;
    }

    for (int it = 0; it < 16; ++it) {
        __syncthreads();
        int buf = it & 1;
        float4 nx0, nx1; half8 nh0, nh1, nl0, nl1;
        bool have = (it + 1) < 16;
        if (have) {
            int k0 = (it + 1) * 32;
            nx0 = *(const float4*)(xsrc + k0);
            nx1 = *(const float4*)(xsrc + k0 + 4);
            nh0 = *(const half8*)(whsrc + k0);
            nh1 = *(const half8*)(whsrc + k0 + 8);
            nl0 = *(const half8*)(wlsrc + k0);
            nl1 = *(const half8*)(wlsrc + k0 + 8);
        }
        // A fragment: read 8 f32, split
        const float* xb = xs + buf * 2304;
        float4 f0 = *(const float4*)&xb[(w * 16 + lr) * 36 + lg * 8];
        float4 f1 = *(const float4*)&xb[(w * 16 + lr) * 36 + lg * 8 + 4];
        float fv[8] = {f0.x, f0.y, f0.z, f0.w, f1.x, f1.y, f1.z, f1.w};
        half8 ah, al;
#pragma unroll
        for (int j = 0; j < 8; ++j) {
            _Float16 h = (_Float16)fv[j];
            ah[j] = h;
            al[j] = (_Float16)((fv[j] - (float)h) * 4096.0f);
        }
        const _Float16* whb = Wh + buf * 5120;
        const _Float16* wlb = Wl + buf * 5120;
#pragma unroll
        for (int set = 0; set < 8; ++set) {
            int bcol = set * 16 + lr;
            half8 bh = *(const half8*)&whb[bcol * 40 + lg * 8];
            half8 bl = *(const half8*)&wlb[bcol * 40 + lg * 8];
            c0[set] = __builtin_amdgcn_mfma_f32_16x16x32_f16(ah, bh, c0[set], 0, 0, 0);
            c1[set] = __builtin_amdgcn_mfma_f32_16x16x32_f16(ah, bl, c1[set], 0, 0, 0);
            c1[set] = __builtin_amdgcn_mfma_f32_16x16x32_f16(al, bh, c1[set], 0, 0, 0);
        }
        __syncthreads();
        if (have) {
            *(float4*)&xs[(buf ^ 1) * 2304 + xr_r * 36 + xr_c] = nx0;
            *(float4*)&xs[(buf ^ 1) * 2304 + xr_r * 36 + xr_c + 4] = nx1;
            _Float16* dh = Wh + (buf ^ 1) * 5120 + wcol * 40 + wh_h * 16;
            _Float16* dl = Wl + (buf ^ 1) * 5120 + wcol * 40 + wh_h * 16;
            *(half8*)(dh) = nh0; *(half8*)(dh + 8) = nh1;
            *(half8*)(dl) = nl0; *(half8*)(dl + 8) = nl1;
        }
    }
    __syncthreads();

    // epilogue: combine, normalize (per row over 128 cols), dump to LDS, re-read, split
    float* few = (float*)smem + w * 2112;           // [16][132]
    float ss[4] = {0.f, 0.f, 0.f, 0.f};
    float vv[8][4];
#pragma unroll
    for (int set = 0; set < 8; ++set)
#pragma unroll
        for (int r = 0; r < 4; ++r) {
            float v = fmaf(c1[set][r], SCALE_DN, c0[set][r]);
            vv[set][r] = v;
            ss[r] = fmaf(v, v, ss[r]);
        }
#pragma unroll
    for (int r = 0; r < 4; ++r) {
#pragma unroll
        for (int m = 1; m < 16; m <<= 1) ss[r] += __shfl_xor(ss[r], m);
    }
    float rn[4];
#pragma unroll
    for (int r = 0; r < 4; ++r) rn[r] = rsqrtf(ss[r]);
#pragma unroll
    for (int set = 0; set < 8; ++set)
#pragma unroll
        for (int r = 0; r < 4; ++r)
            few[(4 * lg + r) * 132 + set * 16 + lr] = vv[set][r] * rn[r];
    __syncthreads();
    int l = t & 63;
    int rr = l >> 2, q = l & 3;
    size_t btg = (size_t)(row0 + w * 16 + rr);
    size_t dst = (btg * 4 + sIdx) * DDIM + q * 32;
#pragma unroll
    for (int g = 0; g < 4; ++g) {
        half8 oh, ol;
#pragma unroll
        for (int j = 0; j < 8; ++j) {
            float f = few[rr * 132 + q * 32 + g * 8 + j];
            _Float16 h = (_Float16)f;
            oh[j] = h;
            ol[j] = (_Float16)((f - (float)h) * 4096.0f);
        }
        *(half8*)(fhi + dst + g * 8) = oh;
        *(half8*)(flo + dst + g * 8) = ol;
    }
}

// ---------------- sim + argmax: feat[32768][128] x cb[8192][128]^T, f16x3 MFMA ----------
// 256 blocks x 4 waves; wave owns 32 feat rows (2 A-sets in regs); scans all 8192 codes.
__global__ __launch_bounds__(256) void sim_argmax_mfma(const _Float16* __restrict__ fhi,
                                                       const _Float16* __restrict__ flo,
                                                       const _Float16* __restrict__ chi,
                                                       const _Float16* __restrict__ clo,
                                                       int* __restrict__ out) {
    __shared__ _Float16 Bh[2][2048];
    __shared__ _Float16 Bl[2][2048];
    __shared__ float redv[128][17];
    __shared__ int   redi[128][17];

    int t = threadIdx.x;
    int w = t >> 6, lr = t & 15, lg = (t >> 4) & 3;
    int row0 = blockIdx.x * 128;

    // A fragments (2 sets x 4 kt), resident whole kernel
    half8 ahi[2][4], alo[2][4];
#pragma unroll
    for (int s = 0; s < 2; ++s)
#pragma unroll
        for (int kt = 0; kt < 4; ++kt) {
            size_t off = (size_t)(row0 + w * 32 + s * 16 + lr) * DDIM + kt * 32 + lg * 8;
            ahi[s][kt] = *(const half8*)(fhi + off);
            alo[s][kt] = *(const half8*)(flo + off);
        }

    int roff[4];
#pragma unroll
    for (int kt = 0; kt < 4; ++kt)
        roff[kt] = lr * 128 + (((kt << 2) | lg) ^ (lr & 7)) * 8;

    const half8* chv = (const half8*)chi;   // 256 half8 per 16-code tile
    const half8* clv = (const half8*)clo;

    float best[2][4];
    int btile[2][4];
#pragma unroll
    for (int s = 0; s < 2; ++s)
#pragma unroll
        for (int r = 0; r < 4; ++r) { best[s][r] = -1e30f; btile[s][r] = 0; }

    // prologue: stage tile 0 into buf 0 (ws already in LDS-image order)
    *(half8*)&Bh[0][t * 8] = chv[t];
    *(half8*)&Bl[0][t * 8] = clv[t];

    const int NT = NEMBED / 16;   // 512
    for (int it = 0; it < NT; ++it) {
        __syncthreads();
        int buf = it & 1;
        half8 nh, nl;
        bool have = (it + 1) < NT;
        if (have) {
            nh = chv[(it + 1) * 256 + t];
            nl = clv[(it + 1) * 256 + t];
        }
        f32x4 a0_0 = {0.f,0.f,0.f,0.f}, a0_1 = a0_0, a1_0 = a0_0, a1_1 = a0_0;
#pragma unroll
        for (int kt = 0; kt < 4; ++kt) {
            half8 bh = *(const half8*)&Bh[buf][roff[kt]];
            half8 bl = *(const half8*)&Bl[buf][roff[kt]];
            a0_0 = __builtin_amdgcn_mfma_f32_16x16x32_f16(ahi[0][kt], bh, a0_0, 0, 0, 0);
            a1_0 = __builtin_amdgcn_mfma_f32_16x16x32_f16(ahi[0][kt], bl, a1_0, 0, 0, 0);
            a1_0 = __builtin_amdgcn_mfma_f32_16x16x32_f16(alo[0][kt], bh, a1_0, 0, 0, 0);
            a0_1 = __builtin_amdgcn_mfma_f32_16x16x32_f16(ahi[1][kt], bh, a0_1, 0, 0, 0);
            a1_1 = __builtin_amdgcn_mfma_f32_16x16x32_f16(ahi[1][kt], bl, a1_1, 0, 0, 0);
            a1_1 = __builtin_amdgcn_mfma_f32_16x16x32_f16(alo[1][kt], bh, a1_1, 0, 0, 0);
        }
#pragma unroll
        for (int r = 0; r < 4; ++r) {
            float v0 = fmaf(a1_0[r], SCALE_DN, a0_0[r]);
            if (v0 > best[0][r]) { best[0][r] = v0; btile[0][r] = it; }
            float v1 = fmaf(a1_1[r], SCALE_DN, a0_1[r]);
            if (v1 > best[1][r]) { best[1][r] = v1; btile[1][r] = it; }
        }
        if (have) {
            *(half8*)&Bh[buf ^ 1][t * 8] = nh;
            *(half8*)&Bl[buf ^ 1][t * 8] = nl;
        }
    }

#pragma unroll
    for (int s = 0; s < 2; ++s)
#pragma unroll
        for (int r = 0; r < 4; ++r) {
            int row = w * 32 + s * 16 + 4 * lg + r;
            redv[row][lr] = best[s][r];
            redi[row][lr] = btile[s][r] * 16 + lr;
        }
    __syncthreads();
    if (t < 128) {
        float bv = redv[t][0]; int bi = redi[t][0];
#pragma unroll
        for (int c = 1; c < 16; ++c) {
            float v = redv[t][c]; int ii = redi[t][c];
            if (v > bv || (v == bv && ii < bi)) { bv = v; bi = ii; }
        }
        out[row0 + t] = bi;
    }
}

extern "C" void kernel_launch(void* const* d_in, const int* in_sizes, int n_in,
                              void* d_out, int out_size, void* d_ws, size_t ws_size,
                              hipStream_t stream) {
    const float* x    = (const float*)d_in[0];   // [32,256,512]
    const float* proj = (const float*)d_in[1];   // [512,128]
    const float* cb   = (const float*)d_in[2];   // [1,8192,128]
    const int*   rm   = (const int*)d_in[3];     // [257]
    int* out = (int*)d_out;                      // [32,256,4,1] int32

    char* wsb = (char*)d_ws;
    float*    Kmat = (float*)(wsb + 0);              // 8 KB
    float*    W    = (float*)(wsb + 8192);           // 1 MB
    _Float16* Wth  = (_Float16*)(wsb + 1056768);     // 512 KB
    _Float16* Wtl  = (_Float16*)(wsb + 1581056);     // 512 KB
    _Float16* chi  = (_Float16*)(wsb + 2105344);     // 2 MB (DMA/LDS-image order)
    _Float16* clo  = (_Float16*)(wsb + 4202496);     // 2 MB
    _Float16* fhi  = (_Float16*)(wsb + 6299648);     // 8 MB
    _Float16* flo  = (_Float16*)(wsb + 14688256);    // 8 MB  (end ~23 MB)

    build_K_kernel<<<1, 512, 0, stream>>>(rm, Kmat);
    build_W_kernel<<<dim3(32, 4), 128, 0, stream>>>(proj, Kmat, W);
    wsplit_kernel<<<dim3(8, 8), 256, 0, stream>>>(W, Wth, Wtl);
    cbsplit_kernel<<<NEMBED / 4, 256, 0, stream>>>(cb, chi, clo);
    fused_feat<<<dim3(128, 4), 256, 0, stream>>>(x, Wth, Wtl, fhi, flo);
    sim_argmax_mfma<<<256, 256, 0, stream>>>(fhi, flo, chi, clo, out);
}

// Round 4
// 345.762 us; speedup vs baseline: 1.4868x; 1.4868x over previous
//
#include <hip/hip_runtime.h>
#include <math.h>

#define BT 8192      // B*T
#define NDIM 512     // INPUT_DIM
#define NFREQ 257
#define DDIM 128     // VQ_DIM
#define NEMBED 8192
#define NQ 4         // codebook quarters
#define ROWS 32768   // BT*4 splits

typedef _Float16 half8 __attribute__((ext_vector_type(8)));
typedef _Float16 half2v __attribute__((ext_vector_type(2)));
typedef float f32x4 __attribute__((ext_vector_type(4)));

#define SCALE_DN 2.44140625e-4f   // 2^-12

// ---------------- K table: K_s[delta] = sum_{f: rm[f]==s} w_f cos(2*pi*f*delta/512) ----
__global__ __launch_bounds__(512) void build_K_kernel(const int* __restrict__ rm,
                                                      float* __restrict__ Kmat) {
    __shared__ float ctab[512];
    __shared__ int rms[NFREQ];
    int t = threadIdx.x;
    ctab[t] = cospif((float)t * (1.0f / 256.0f));   // cos(2*pi*t/512)
    if (t < NFREQ) rms[t] = rm[t];
    __syncthreads();
    float acc0 = 0.f, acc1 = 0.f, acc2 = 0.f, acc3 = 0.f;
    for (int f = 0; f < NFREQ; ++f) {
        float w = (f == 0 || f == 256) ? 1.0f : 2.0f;
        float c = w * ctab[(f * t) & 511];
        int s = rms[f];
        acc0 += (s == 0) ? c : 0.0f;
        acc1 += (s == 1) ? c : 0.0f;
        acc2 += (s == 2) ? c : 0.0f;
        acc3 += (s == 3) ? c : 0.0f;
    }
    const float sc = 1.0f / 512.0f;
    Kmat[0 * 512 + t] = acc0 * sc;
    Kmat[1 * 512 + t] = acc1 * sc;
    Kmat[2 * 512 + t] = acc2 * sc;
    Kmat[3 * 512 + t] = acc3 * sc;
}

// ------- W^T split: Wth/Wtl[c][k] = f16split(256 * sum_p proj[p][c&127] K_s[(p-k)&511]) -
// 8 k-rows per block; register window over Ks; writes transposed hi/lo directly.
__global__ __launch_bounds__(128) void build_W_split(const float* __restrict__ proj,
                                                     const float* __restrict__ Kmat,
                                                     _Float16* __restrict__ Wth,
                                                     _Float16* __restrict__ Wtl) {
    int nt = blockIdx.x, s = blockIdx.y, d = threadIdx.x;
    int n0 = nt * 8;
    __shared__ float Ks[512];
    for (int i = d; i < 512; i += 128) Ks[i] = Kmat[s * 512 + i];
    __syncthreads();
    float acc[8] = {};
    for (int p16 = 0; p16 < 512; p16 += 16) {
        float wv[23];
#pragma unroll
        for (int j2 = 0; j2 < 23; ++j2) wv[j2] = Ks[(p16 - n0 + j2 - 7) & 511];
#pragma unroll
        for (int j = 0; j < 16; ++j) {
            float xp = proj[(p16 + j) * DDIM + d];
#pragma unroll
            for (int i = 0; i < 8; ++i)
                acc[i] = fmaf(xp, wv[7 + j - i], acc[i]);
        }
    }
    size_t cbase = (size_t)(s * DDIM + d) * 512 + n0;
#pragma unroll
    for (int i = 0; i < 8; ++i) {
        float f = acc[i] * 256.0f;          // pre-scale: dodge f16 denormals (norm cancels)
        _Float16 h = (_Float16)f;
        Wth[cbase + i] = h;
        Wtl[cbase + i] = (_Float16)((f - (float)h) * 4096.0f);
    }
}

// ---------------- codebook: normalize + f16 hi/lo split, written in DMA/LDS-image order -
// ws layout: [tile=code>>4][row=code&15][slot cp][8 f16], slot cp holds chunk cp^(row&7)
__global__ __launch_bounds__(256) void cbsplit_kernel(const float* __restrict__ cb,
                                                      _Float16* __restrict__ chi,
                                                      _Float16* __restrict__ clo) {
    int code = blockIdx.x * 4 + (threadIdx.x >> 6);
    int l = threadIdx.x & 63;
    float2 v = ((const float2*)(cb + (size_t)code * DDIM))[l];
    float ss = fmaf(v.x, v.x, v.y * v.y);
#pragma unroll
    for (int m = 32; m; m >>= 1) ss += __shfl_xor(ss, m);
    float r = 1.0f / sqrtf(ss);
    float a = v.x * r, b = v.y * r;
    _Float16 ha = (_Float16)a, hb = (_Float16)b;
    half2v hv = {ha, hb};
    half2v lv = {(_Float16)((a - (float)ha) * 4096.0f), (_Float16)((b - (float)hb) * 4096.0f)};
    int row = code & 15, tile = code >> 4;
    int cp = (l >> 2) ^ (row & 7);
    size_t base = (size_t)tile * 2048 + row * 128 + cp * 8 + (l & 3) * 2;
    *(half2v*)(chi + base) = hv;
    *(half2v*)(clo + base) = lv;
}

// ---------------- fused feat: feat = x @ W (f16x3 MFMA), row-normalize, split hi/lo -----
__global__ __launch_bounds__(256) void fused_feat(const float* __restrict__ x,
                                                  const _Float16* __restrict__ Wth,
                                                  const _Float16* __restrict__ Wtl,
                                                  _Float16* __restrict__ fhi,
                                                  _Float16* __restrict__ flo) {
    __shared__ __align__(16) char smem[59392];
    float* xs = (float*)smem;                       // [2][64][36] f32
    _Float16* Wh = (_Float16*)(smem + 18432);       // [2][128][40] f16
    _Float16* Wl = (_Float16*)(smem + 38912);       // [2][128][40] f16

    int t = threadIdx.x;
    int w = t >> 6, lr = t & 15, lg = (t >> 4) & 3;
    int row0 = blockIdx.x * 64;
    int sIdx = blockIdx.y;

    int xr_r = t >> 2, xr_c = (t & 3) * 8;
    int wcol = t >> 1, wh_h = t & 1;
    const float* xsrc = x + (size_t)(row0 + xr_r) * NDIM + xr_c;
    const _Float16* whsrc = Wth + (size_t)(sIdx * 128 + wcol) * 512 + wh_h * 16;
    const _Float16* wlsrc = Wtl + (size_t)(sIdx * 128 + wcol) * 512 + wh_h * 16;

    f32x4 c0[8], c1[8];
#pragma unroll
    for (int i = 0; i < 8; ++i) { c0[i] = (f32x4){0.f,0.f,0.f,0.f}; c1[i] = c0[i]; }

    {
        float4 a0 = *(const float4*)(xsrc);
        float4 a1 = *(const float4*)(xsrc + 4);
        *(float4*)&xs[xr_r * 36 + xr_c] = a0;
        *(float4*)&xs[xr_r * 36 + xr_c + 4] = a1;
        half8 h0 = *(const half8*)(whsrc);
        half8 h1 = *(const half8*)(whsrc + 8);
        half8 l0 = *(const half8*)(wlsrc);
        half8 l1 = *(const half8*)(wlsrc + 8);
        *(half8*)&Wh[wcol * 40 + wh_h * 16] = h0;
        *(half8*)&Wh[wcol * 40 + wh_h * 16 + 8] = h1;
        *(half8*)&Wl[wcol * 40 + wh_h * 16] = l0;
        *(half8*)&Wl[wcol * 40 + wh_h * 16 + 8] = l1;
    }

    for (int it = 0; it < 16; ++it) {
        __syncthreads();
        int buf = it & 1;
        float4 nx0, nx1; half8 nh0, nh1, nl0, nl1;
        bool have = (it + 1) < 16;
        if (have) {
            int k0 = (it + 1) * 32;
            nx0 = *(const float4*)(xsrc + k0);
            nx1 = *(const float4*)(xsrc + k0 + 4);
            nh0 = *(const half8*)(whsrc + k0);
            nh1 = *(const half8*)(whsrc + k0 + 8);
            nl0 = *(const half8*)(wlsrc + k0);
            nl1 = *(const half8*)(wlsrc + k0 + 8);
        }
        const float* xb = xs + buf * 2304;
        float4 f0 = *(const float4*)&xb[(w * 16 + lr) * 36 + lg * 8];
        float4 f1 = *(const float4*)&xb[(w * 16 + lr) * 36 + lg * 8 + 4];
        float fv[8] = {f0.x, f0.y, f0.z, f0.w, f1.x, f1.y, f1.z, f1.w};
        half8 ah, al;
#pragma unroll
        for (int j = 0; j < 8; ++j) {
            _Float16 h = (_Float16)fv[j];
            ah[j] = h;
            al[j] = (_Float16)((fv[j] - (float)h) * 4096.0f);
        }
        const _Float16* whb = Wh + buf * 5120;
        const _Float16* wlb = Wl + buf * 5120;
#pragma unroll
        for (int set = 0; set < 8; ++set) {
            int bcol = set * 16 + lr;
            half8 bh = *(const half8*)&whb[bcol * 40 + lg * 8];
            half8 bl = *(const half8*)&wlb[bcol * 40 + lg * 8];
            c0[set] = __builtin_amdgcn_mfma_f32_16x16x32_f16(ah, bh, c0[set], 0, 0, 0);
            c1[set] = __builtin_amdgcn_mfma_f32_16x16x32_f16(ah, bl, c1[set], 0, 0, 0);
            c1[set] = __builtin_amdgcn_mfma_f32_16x16x32_f16(al, bh, c1[set], 0, 0, 0);
        }
        __syncthreads();
        if (have) {
            *(float4*)&xs[(buf ^ 1) * 2304 + xr_r * 36 + xr_c] = nx0;
            *(float4*)&xs[(buf ^ 1) * 2304 + xr_r * 36 + xr_c + 4] = nx1;
            _Float16* dh = Wh + (buf ^ 1) * 5120 + wcol * 40 + wh_h * 16;
            _Float16* dl = Wl + (buf ^ 1) * 5120 + wcol * 40 + wh_h * 16;
            *(half8*)(dh) = nh0; *(half8*)(dh + 8) = nh1;
            *(half8*)(dl) = nl0; *(half8*)(dl + 8) = nl1;
        }
    }
    __syncthreads();

    float* few = (float*)smem + w * 2112;           // [16][132]
    float ss[4] = {0.f, 0.f, 0.f, 0.f};
    float vv[8][4];
#pragma unroll
    for (int set = 0; set < 8; ++set)
#pragma unroll
        for (int r = 0; r < 4; ++r) {
            float v = fmaf(c1[set][r], SCALE_DN, c0[set][r]);
            vv[set][r] = v;
            ss[r] = fmaf(v, v, ss[r]);
        }
#pragma unroll
    for (int r = 0; r < 4; ++r) {
#pragma unroll
        for (int m = 1; m < 16; m <<= 1) ss[r] += __shfl_xor(ss[r], m);
    }
    float rn[4];
#pragma unroll
    for (int r = 0; r < 4; ++r) rn[r] = rsqrtf(ss[r]);
#pragma unroll
    for (int set = 0; set < 8; ++set)
#pragma unroll
        for (int r = 0; r < 4; ++r)
            few[(4 * lg + r) * 132 + set * 16 + lr] = vv[set][r] * rn[r];
    __syncthreads();
    int l = t & 63;
    int rr = l >> 2, q = l & 3;
    size_t btg = (size_t)(row0 + w * 16 + rr);
    size_t dst = (btg * 4 + sIdx) * DDIM + q * 32;
#pragma unroll
    for (int g = 0; g < 4; ++g) {
        half8 oh, ol;
#pragma unroll
        for (int j = 0; j < 8; ++j) {
            float f = few[rr * 132 + q * 32 + g * 8 + j];
            _Float16 h = (_Float16)f;
            oh[j] = h;
            ol[j] = (_Float16)((f - (float)h) * 4096.0f);
        }
        *(half8*)(fhi + dst + g * 8) = oh;
        *(half8*)(flo + dst + g * 8) = ol;
    }
}

// ---------------- sim + argmax partial: 128 feat rows x 2048-code quarter ---------------
// grid (256 row-tiles, 4 quarters); 4 waves x 32 rows; writes per-row (val,idx) partials.
__global__ __launch_bounds__(256) void sim_argmax_part(const _Float16* __restrict__ fhi,
                                                       const _Float16* __restrict__ flo,
                                                       const _Float16* __restrict__ chi,
                                                       const _Float16* __restrict__ clo,
                                                       float* __restrict__ pv,
                                                       int* __restrict__ pi) {
    __shared__ _Float16 Bh[2][2048];
    __shared__ _Float16 Bl[2][2048];
    __shared__ float redv[128][17];
    __shared__ int   redi[128][17];

    int t = threadIdx.x;
    int w = t >> 6, lr = t & 15, lg = (t >> 4) & 3;
    int row0 = blockIdx.x * 128;
    int q = blockIdx.y;

    half8 ahi[2][4], alo[2][4];
#pragma unroll
    for (int s = 0; s < 2; ++s)
#pragma unroll
        for (int kt = 0; kt < 4; ++kt) {
            size_t off = (size_t)(row0 + w * 32 + s * 16 + lr) * DDIM + kt * 32 + lg * 8;
            ahi[s][kt] = *(const half8*)(fhi + off);
            alo[s][kt] = *(const half8*)(flo + off);
        }

    int roff[4];
#pragma unroll
    for (int kt = 0; kt < 4; ++kt)
        roff[kt] = lr * 128 + (((kt << 2) | lg) ^ (lr & 7)) * 8;

    const half8* chv = (const half8*)chi + (size_t)q * 32768;   // quarter base
    const half8* clv = (const half8*)clo + (size_t)q * 32768;

    float best[2][4];
    int btile[2][4];
#pragma unroll
    for (int s = 0; s < 2; ++s)
#pragma unroll
        for (int r = 0; r < 4; ++r) { best[s][r] = -1e30f; btile[s][r] = 0; }

    *(half8*)&Bh[0][t * 8] = chv[t];
    *(half8*)&Bl[0][t * 8] = clv[t];

    const int NT = NEMBED / (16 * NQ);   // 128 tiles per quarter
    for (int it = 0; it < NT; ++it) {
        __syncthreads();
        int buf = it & 1;
        half8 nh, nl;
        bool have = (it + 1) < NT;
        if (have) {
            nh = chv[(it + 1) * 256 + t];
            nl = clv[(it + 1) * 256 + t];
        }
        f32x4 a0_0 = {0.f,0.f,0.f,0.f}, a0_1 = a0_0, a1_0 = a0_0, a1_1 = a0_0;
#pragma unroll
        for (int kt = 0; kt < 4; ++kt) {
            half8 bh = *(const half8*)&Bh[buf][roff[kt]];
            half8 bl = *(const half8*)&Bl[buf][roff[kt]];
            a0_0 = __builtin_amdgcn_mfma_f32_16x16x32_f16(ahi[0][kt], bh, a0_0, 0, 0, 0);
            a1_0 = __builtin_amdgcn_mfma_f32_16x16x32_f16(ahi[0][kt], bl, a1_0, 0, 0, 0);
            a1_0 = __builtin_amdgcn_mfma_f32_16x16x32_f16(alo[0][kt], bh, a1_0, 0, 0, 0);
            a0_1 = __builtin_amdgcn_mfma_f32_16x16x32_f16(ahi[1][kt], bh, a0_1, 0, 0, 0);
            a1_1 = __builtin_amdgcn_mfma_f32_16x16x32_f16(ahi[1][kt], bl, a1_1, 0, 0, 0);
            a1_1 = __builtin_amdgcn_mfma_f32_16x16x32_f16(alo[1][kt], bh, a1_1, 0, 0, 0);
        }
#pragma unroll
        for (int r = 0; r < 4; ++r) {
            float v0 = fmaf(a1_0[r], SCALE_DN, a0_0[r]);
            if (v0 > best[0][r]) { best[0][r] = v0; btile[0][r] = it; }
            float v1 = fmaf(a1_1[r], SCALE_DN, a0_1[r]);
            if (v1 > best[1][r]) { best[1][r] = v1; btile[1][r] = it; }
        }
        if (have) {
            *(half8*)&Bh[buf ^ 1][t * 8] = nh;
            *(half8*)&Bl[buf ^ 1][t * 8] = nl;
        }
    }

#pragma unroll
    for (int s = 0; s < 2; ++s)
#pragma unroll
        for (int r = 0; r < 4; ++r) {
            int row = w * 32 + s * 16 + 4 * lg + r;
            redv[row][lr] = best[s][r];
            redi[row][lr] = q * (NEMBED / NQ) + btile[s][r] * 16 + lr;
        }
    __syncthreads();
    if (t < 128) {
        float bv = redv[t][0]; int bi = redi[t][0];
#pragma unroll
        for (int c = 1; c < 16; ++c) {
            float v = redv[t][c]; int ii = redi[t][c];
            if (v > bv || (v == bv && ii < bi)) { bv = v; bi = ii; }
        }
        pv[(size_t)q * ROWS + row0 + t] = bv;
        pi[(size_t)q * ROWS + row0 + t] = bi;
    }
}

// ---------------- merge 4 quarter-candidates per row ------------------------------------
__global__ __launch_bounds__(256) void merge_argmax(const float* __restrict__ pv,
                                                    const int* __restrict__ pi,
                                                    int* __restrict__ out) {
    int row = blockIdx.x * 256 + threadIdx.x;
    float bv = pv[row]; int bi = pi[row];
#pragma unroll
    for (int q = 1; q < NQ; ++q) {
        float v = pv[(size_t)q * ROWS + row];
        if (v > bv) { bv = v; bi = pi[(size_t)q * ROWS + row]; }   // ties -> lower q wins
    }
    out[row] = bi;
}

extern "C" void kernel_launch(void* const* d_in, const int* in_sizes, int n_in,
                              void* d_out, int out_size, void* d_ws, size_t ws_size,
                              hipStream_t stream) {
    const float* x    = (const float*)d_in[0];   // [32,256,512]
    const float* proj = (const float*)d_in[1];   // [512,128]
    const float* cb   = (const float*)d_in[2];   // [1,8192,128]
    const int*   rm   = (const int*)d_in[3];     // [257]
    int* out = (int*)d_out;                      // [32,256,4,1] int32

    char* wsb = (char*)d_ws;
    float*    Kmat = (float*)(wsb + 0);              // 8 KB
    _Float16* Wth  = (_Float16*)(wsb + 8192);        // 512 KB
    _Float16* Wtl  = (_Float16*)(wsb + 532480);      // 512 KB
    _Float16* chi  = (_Float16*)(wsb + 1056768);     // 2 MB (DMA/LDS-image order)
    _Float16* clo  = (_Float16*)(wsb + 3153920);     // 2 MB
    _Float16* fhi  = (_Float16*)(wsb + 5251072);     // 8 MB
    _Float16* flo  = (_Float16*)(wsb + 13639680);    // 8 MB
    float*    pv   = (float*)(wsb + 22028288);       // 512 KB
    int*      pi   = (int*)(wsb + 22552576);         // 512 KB (end ~23 MB)

    build_K_kernel<<<1, 512, 0, stream>>>(rm, Kmat);
    build_W_split<<<dim3(64, 4), 128, 0, stream>>>(proj, Kmat, Wth, Wtl);
    cbsplit_kernel<<<NEMBED / 4, 256, 0, stream>>>(cb, chi, clo);
    fused_feat<<<dim3(128, 4), 256, 0, stream>>>(x, Wth, Wtl, fhi, flo);
    sim_argmax_part<<<dim3(ROWS / 128, NQ), 256, 0, stream>>>(fhi, flo, chi, clo, pv, pi);
    merge_argmax<<<ROWS / 256, 256, 0, stream>>>(pv, pi, out);
}

// Round 5
// 300.081 us; speedup vs baseline: 1.7132x; 1.1522x over previous
//
#include <hip/hip_runtime.h>
#include <math.h>

#define BT 8192      // B*T
#define NDIM 512     // INPUT_DIM
#define NFREQ 257
#define DDIM 128     // VQ_DIM
#define NEMBED 8192
#define NQ 4         // codebook quarters
#define ROWS 32768   // BT*4 splits

typedef _Float16 half8 __attribute__((ext_vector_type(8)));
typedef _Float16 half2v __attribute__((ext_vector_type(2)));
typedef float f32x4 __attribute__((ext_vector_type(4)));

#define SCALE_DN 2.44140625e-4f   // 2^-12

// ---------------- K table: K_s[delta] = sum_{f: rm[f]==s} w_f cos(2*pi*f*delta/512) ----
__global__ __launch_bounds__(512) void build_K_kernel(const int* __restrict__ rm,
                                                      float* __restrict__ Kmat) {
    __shared__ float ctab[512];
    __shared__ int rms[NFREQ];
    int t = threadIdx.x;
    ctab[t] = cospif((float)t * (1.0f / 256.0f));   // cos(2*pi*t/512)
    if (t < NFREQ) rms[t] = rm[t];
    __syncthreads();
    float acc0 = 0.f, acc1 = 0.f, acc2 = 0.f, acc3 = 0.f;
    for (int f = 0; f < NFREQ; ++f) {
        float w = (f == 0 || f == 256) ? 1.0f : 2.0f;
        float c = w * ctab[(f * t) & 511];
        int s = rms[f];
        acc0 += (s == 0) ? c : 0.0f;
        acc1 += (s == 1) ? c : 0.0f;
        acc2 += (s == 2) ? c : 0.0f;
        acc3 += (s == 3) ? c : 0.0f;
    }
    const float sc = 1.0f / 512.0f;
    Kmat[0 * 512 + t] = acc0 * sc;
    Kmat[1 * 512 + t] = acc1 * sc;
    Kmat[2 * 512 + t] = acc2 * sc;
    Kmat[3 * 512 + t] = acc3 * sc;
}

// ------- W^T split: Wth/Wtl[c][k] = f16split(256 * sum_p proj[p][c&127] K_s[(p-k)&511]) -
__global__ __launch_bounds__(128) void build_W_split(const float* __restrict__ proj,
                                                     const float* __restrict__ Kmat,
                                                     _Float16* __restrict__ Wth,
                                                     _Float16* __restrict__ Wtl) {
    int nt = blockIdx.x, s = blockIdx.y, d = threadIdx.x;
    int n0 = nt * 8;
    __shared__ float Ks[512];
    for (int i = d; i < 512; i += 128) Ks[i] = Kmat[s * 512 + i];
    __syncthreads();
    float acc[8] = {};
    for (int p16 = 0; p16 < 512; p16 += 16) {
        float wv[23];
#pragma unroll
        for (int j2 = 0; j2 < 23; ++j2) wv[j2] = Ks[(p16 - n0 + j2 - 7) & 511];
#pragma unroll
        for (int j = 0; j < 16; ++j) {
            float xp = proj[(p16 + j) * DDIM + d];
#pragma unroll
            for (int i = 0; i < 8; ++i)
                acc[i] = fmaf(xp, wv[7 + j - i], acc[i]);
        }
    }
    size_t cbase = (size_t)(s * DDIM + d) * 512 + n0;
#pragma unroll
    for (int i = 0; i < 8; ++i) {
        float f = acc[i] * 256.0f;          // pre-scale: dodge f16 denormals (norm cancels)
        _Float16 h = (_Float16)f;
        Wth[cbase + i] = h;
        Wtl[cbase + i] = (_Float16)((f - (float)h) * 4096.0f);
    }
}

// ---------------- codebook: normalize + f16 hi/lo split, written in DMA/LDS-image order -
__global__ __launch_bounds__(256) void cbsplit_kernel(const float* __restrict__ cb,
                                                      _Float16* __restrict__ chi,
                                                      _Float16* __restrict__ clo) {
    int code = blockIdx.x * 4 + (threadIdx.x >> 6);
    int l = threadIdx.x & 63;
    float2 v = ((const float2*)(cb + (size_t)code * DDIM))[l];
    float ss = fmaf(v.x, v.x, v.y * v.y);
#pragma unroll
    for (int m = 32; m; m >>= 1) ss += __shfl_xor(ss, m);
    float r = 1.0f / sqrtf(ss);
    float a = v.x * r, b = v.y * r;
    _Float16 ha = (_Float16)a, hb = (_Float16)b;
    half2v hv = {ha, hb};
    half2v lv = {(_Float16)((a - (float)ha) * 4096.0f), (_Float16)((b - (float)hb) * 4096.0f)};
    int row = code & 15, tile = code >> 4;
    int cp = (l >> 2) ^ (row & 7);
    size_t base = (size_t)tile * 2048 + row * 128 + cp * 8 + (l & 3) * 2;
    *(half2v*)(chi + base) = hv;
    *(half2v*)(clo + base) = lv;
}

// ---------------- fused feat: feat = x @ W (f16x3 MFMA), row-normalize, split hi/lo -----
__global__ __launch_bounds__(256) void fused_feat(const float* __restrict__ x,
                                                  const _Float16* __restrict__ Wth,
                                                  const _Float16* __restrict__ Wtl,
                                                  _Float16* __restrict__ fhi,
                                                  _Float16* __restrict__ flo) {
    __shared__ __align__(16) char smem[59392];
    float* xs = (float*)smem;                       // [2][64][36] f32
    _Float16* Wh = (_Float16*)(smem + 18432);       // [2][128][40] f16
    _Float16* Wl = (_Float16*)(smem + 38912);       // [2][128][40] f16

    int t = threadIdx.x;
    int w = t >> 6, lr = t & 15, lg = (t >> 4) & 3;
    int row0 = blockIdx.x * 64;
    int sIdx = blockIdx.y;

    int xr_r = t >> 2, xr_c = (t & 3) * 8;
    int wcol = t >> 1, wh_h = t & 1;
    const float* xsrc = x + (size_t)(row0 + xr_r) * NDIM + xr_c;
    const _Float16* whsrc = Wth + (size_t)(sIdx * 128 + wcol) * 512 + wh_h * 16;
    const _Float16* wlsrc = Wtl + (size_t)(sIdx * 128 + wcol) * 512 + wh_h * 16;

    f32x4 c0[8], c1[8];
#pragma unroll
    for (int i = 0; i < 8; ++i) { c0[i] = (f32x4){0.f,0.f,0.f,0.f}; c1[i] = c0[i]; }

    {
        float4 a0 = *(const float4*)(xsrc);
        float4 a1 = *(const float4*)(xsrc + 4);
        *(float4*)&xs[xr_r * 36 + xr_c] = a0;
        *(float4*)&xs[xr_r * 36 + xr_c + 4] = a1;
        half8 h0 = *(const half8*)(whsrc);
        half8 h1 = *(const half8*)(whsrc + 8);
        half8 l0 = *(const half8*)(wlsrc);
        half8 l1 = *(const half8*)(wlsrc + 8);
        *(half8*)&Wh[wcol * 40 + wh_h * 16] = h0;
        *(half8*)&Wh[wcol * 40 + wh_h * 16 + 8] = h1;
        *(half8*)&Wl[wcol * 40 + wh_h * 16] = l0;
        *(half8*)&Wl[wcol * 40 + wh_h * 16 + 8] = l1;
    }

    for (int it = 0; it < 16; ++it) {
        __syncthreads();
        int buf = it & 1;
        float4 nx0, nx1; half8 nh0, nh1, nl0, nl1;
        bool have = (it + 1) < 16;
        if (have) {
            int k0 = (it + 1) * 32;
            nx0 = *(const float4*)(xsrc + k0);
            nx1 = *(const float4*)(xsrc + k0 + 4);
            nh0 = *(const half8*)(whsrc + k0);
            nh1 = *(const half8*)(whsrc + k0 + 8);
            nl0 = *(const half8*)(wlsrc + k0);
            nl1 = *(const half8*)(wlsrc + k0 + 8);
        }
        const float* xb = xs + buf * 2304;
        float4 f0 = *(const float4*)&xb[(w * 16 + lr) * 36 + lg * 8];
        float4 f1 = *(const float4*)&xb[(w * 16 + lr) * 36 + lg * 8 + 4];
        float fv[8] = {f0.x, f0.y, f0.z, f0.w, f1.x, f1.y, f1.z, f1.w};
        half8 ah, al;
#pragma unroll
        for (int j = 0; j < 8; ++j) {
            _Float16 h = (_Float16)fv[j];
            ah[j] = h;
            al[j] = (_Float16)((fv[j] - (float)h) * 4096.0f);
        }
        const _Float16* whb = Wh + buf * 5120;
        const _Float16* wlb = Wl + buf * 5120;
#pragma unroll
        for (int set = 0; set < 8; ++set) {
            int bcol = set * 16 + lr;
            half8 bh = *(const half8*)&whb[bcol * 40 + lg * 8];
            half8 bl = *(const half8*)&wlb[bcol * 40 + lg * 8];
            c0[set] = __builtin_amdgcn_mfma_f32_16x16x32_f16(ah, bh, c0[set], 0, 0, 0);
            c1[set] = __builtin_amdgcn_mfma_f32_16x16x32_f16(ah, bl, c1[set], 0, 0, 0);
            c1[set] = __builtin_amdgcn_mfma_f32_16x16x32_f16(al, bh, c1[set], 0, 0, 0);
        }
        __syncthreads();
        if (have) {
            *(float4*)&xs[(buf ^ 1) * 2304 + xr_r * 36 + xr_c] = nx0;
            *(float4*)&xs[(buf ^ 1) * 2304 + xr_r * 36 + xr_c + 4] = nx1;
            _Float16* dh = Wh + (buf ^ 1) * 5120 + wcol * 40 + wh_h * 16;
            _Float16* dl = Wl + (buf ^ 1) * 5120 + wcol * 40 + wh_h * 16;
            *(half8*)(dh) = nh0; *(half8*)(dh + 8) = nh1;
            *(half8*)(dl) = nl0; *(half8*)(dl + 8) = nl1;
        }
    }
    __syncthreads();

    float* few = (float*)smem + w * 2112;           // [16][132]
    float ss[4] = {0.f, 0.f, 0.f, 0.f};
    float vv[8][4];
#pragma unroll
    for (int set = 0; set < 8; ++set)
#pragma unroll
        for (int r = 0; r < 4; ++r) {
            float v = fmaf(c1[set][r], SCALE_DN, c0[set][r]);
            vv[set][r] = v;
            ss[r] = fmaf(v, v, ss[r]);
        }
#pragma unroll
    for (int r = 0; r < 4; ++r) {
#pragma unroll
        for (int m = 1; m < 16; m <<= 1) ss[r] += __shfl_xor(ss[r], m);
    }
    float rn[4];
#pragma unroll
    for (int r = 0; r < 4; ++r) rn[r] = rsqrtf(ss[r]);
#pragma unroll
    for (int set = 0; set < 8; ++set)
#pragma unroll
        for (int r = 0; r < 4; ++r)
            few[(4 * lg + r) * 132 + set * 16 + lr] = vv[set][r] * rn[r];
    __syncthreads();
    int l = t & 63;
    int rr = l >> 2, q = l & 3;
    size_t btg = (size_t)(row0 + w * 16 + rr);
    size_t dst = (btg * 4 + sIdx) * DDIM + q * 32;
#pragma unroll
    for (int g = 0; g < 4; ++g) {
        half8 oh, ol;
#pragma unroll
        for (int j = 0; j < 8; ++j) {
            float f = few[rr * 132 + q * 32 + g * 8 + j];
            _Float16 h = (_Float16)f;
            oh[j] = h;
            ol[j] = (_Float16)((f - (float)h) * 4096.0f);
        }
        *(half8*)(fhi + dst + g * 8) = oh;
        *(half8*)(flo + dst + g * 8) = ol;
    }
}

// ---------------- sim + argmax partial: 256 feat rows x 2048-code quarter ---------------
// grid (128 row-tiles, 4 quarters); 4 waves x 64 rows (4 A-sets in regs); 48 MFMA/iter.
__global__ __launch_bounds__(256, 2) void sim_argmax_part(const _Float16* __restrict__ fhi,
                                                          const _Float16* __restrict__ flo,
                                                          const _Float16* __restrict__ chi,
                                                          const _Float16* __restrict__ clo,
                                                          float* __restrict__ pv,
                                                          int* __restrict__ pi) {
    __shared__ _Float16 Bh[2][2048];
    __shared__ _Float16 Bl[2][2048];
    __shared__ float redv[256][17];
    __shared__ int   redi[256][17];

    int t = threadIdx.x;
    int w = t >> 6, lr = t & 15, lg = (t >> 4) & 3;
    int row0 = blockIdx.x * 256;
    int q = blockIdx.y;

    // A fragments (4 sets x 4 kt), resident whole kernel: 128 VGPR
    half8 ahi[4][4], alo[4][4];
#pragma unroll
    for (int s = 0; s < 4; ++s)
#pragma unroll
        for (int kt = 0; kt < 4; ++kt) {
            size_t off = (size_t)(row0 + w * 64 + s * 16 + lr) * DDIM + kt * 32 + lg * 8;
            ahi[s][kt] = *(const half8*)(fhi + off);
            alo[s][kt] = *(const half8*)(flo + off);
        }

    int roff[4];
#pragma unroll
    for (int kt = 0; kt < 4; ++kt)
        roff[kt] = lr * 128 + (((kt << 2) | lg) ^ (lr & 7)) * 8;

    const half8* chv = (const half8*)chi + (size_t)q * 32768;   // quarter base
    const half8* clv = (const half8*)clo + (size_t)q * 32768;

    float best[4][4];
    int btile[4][4];
#pragma unroll
    for (int s = 0; s < 4; ++s)
#pragma unroll
        for (int r = 0; r < 4; ++r) { best[s][r] = -1e30f; btile[s][r] = 0; }

    *(half8*)&Bh[0][t * 8] = chv[t];
    *(half8*)&Bl[0][t * 8] = clv[t];

    const int NT = NEMBED / (16 * NQ);   // 128 tiles per quarter
    for (int it = 0; it < NT; ++it) {
        __syncthreads();
        int buf = it & 1;
        half8 nh, nl;
        bool have = (it + 1) < NT;
        if (have) {
            nh = chv[(it + 1) * 256 + t];
            nl = clv[(it + 1) * 256 + t];
        }
        f32x4 a0[4], a1[4];
#pragma unroll
        for (int s = 0; s < 4; ++s) { a0[s] = (f32x4){0.f,0.f,0.f,0.f}; a1[s] = a0[s]; }
#pragma unroll
        for (int kt = 0; kt < 4; ++kt) {
            half8 bh = *(const half8*)&Bh[buf][roff[kt]];
            half8 bl = *(const half8*)&Bl[buf][roff[kt]];
#pragma unroll
            for (int s = 0; s < 4; ++s) {
                a0[s] = __builtin_amdgcn_mfma_f32_16x16x32_f16(ahi[s][kt], bh, a0[s], 0, 0, 0);
                a1[s] = __builtin_amdgcn_mfma_f32_16x16x32_f16(ahi[s][kt], bl, a1[s], 0, 0, 0);
                a1[s] = __builtin_amdgcn_mfma_f32_16x16x32_f16(alo[s][kt], bh, a1[s], 0, 0, 0);
            }
        }
#pragma unroll
        for (int s = 0; s < 4; ++s)
#pragma unroll
            for (int r = 0; r < 4; ++r) {
                float v = fmaf(a1[s][r], SCALE_DN, a0[s][r]);
                if (v > best[s][r]) { best[s][r] = v; btile[s][r] = it; }
            }
        if (have) {
            *(half8*)&Bh[buf ^ 1][t * 8] = nh;
            *(half8*)&Bl[buf ^ 1][t * 8] = nl;
        }
    }

#pragma unroll
    for (int s = 0; s < 4; ++s)
#pragma unroll
        for (int r = 0; r < 4; ++r) {
            int row = w * 64 + s * 16 + 4 * lg + r;
            redv[row][lr] = best[s][r];
            redi[row][lr] = q * (NEMBED / NQ) + btile[s][r] * 16 + lr;
        }
    __syncthreads();
    {
        float bv = redv[t][0]; int bi = redi[t][0];
#pragma unroll
        for (int c = 1; c < 16; ++c) {
            float v = redv[t][c]; int ii = redi[t][c];
            if (v > bv || (v == bv && ii < bi)) { bv = v; bi = ii; }
        }
        pv[(size_t)q * ROWS + row0 + t] = bv;
        pi[(size_t)q * ROWS + row0 + t] = bi;
    }
}

// ---------------- merge 4 quarter-candidates per row ------------------------------------
__global__ __launch_bounds__(256) void merge_argmax(const float* __restrict__ pv,
                                                    const int* __restrict__ pi,
                                                    int* __restrict__ out) {
    int row = blockIdx.x * 256 + threadIdx.x;
    float bv = pv[row]; int bi = pi[row];
#pragma unroll
    for (int q = 1; q < NQ; ++q) {
        float v = pv[(size_t)q * ROWS + row];
        if (v > bv) { bv = v; bi = pi[(size_t)q * ROWS + row]; }   // ties -> lower q wins
    }
    out[row] = bi;
}

extern "C" void kernel_launch(void* const* d_in, const int* in_sizes, int n_in,
                              void* d_out, int out_size, void* d_ws, size_t ws_size,
                              hipStream_t stream) {
    const float* x    = (const float*)d_in[0];   // [32,256,512]
    const float* proj = (const float*)d_in[1];   // [512,128]
    const float* cb   = (const float*)d_in[2];   // [1,8192,128]
    const int*   rm   = (const int*)d_in[3];     // [257]
    int* out = (int*)d_out;                      // [32,256,4,1] int32

    char* wsb = (char*)d_ws;
    float*    Kmat = (float*)(wsb + 0);              // 8 KB
    _Float16* Wth  = (_Float16*)(wsb + 8192);        // 512 KB
    _Float16* Wtl  = (_Float16*)(wsb + 532480);      // 512 KB
    _Float16* chi  = (_Float16*)(wsb + 1056768);     // 2 MB (DMA/LDS-image order)
    _Float16* clo  = (_Float16*)(wsb + 3153920);     // 2 MB
    _Float16* fhi  = (_Float16*)(wsb + 5251072);     // 8 MB
    _Float16* flo  = (_Float16*)(wsb + 13639680);    // 8 MB
    float*    pv   = (float*)(wsb + 22028288);       // 512 KB
    int*      pi   = (int*)(wsb + 22552576);         // 512 KB (end ~23 MB)

    build_K_kernel<<<1, 512, 0, stream>>>(rm, Kmat);
    build_W_split<<<dim3(64, 4), 128, 0, stream>>>(proj, Kmat, Wth, Wtl);
    cbsplit_kernel<<<NEMBED / 4, 256, 0, stream>>>(cb, chi, clo);
    fused_feat<<<dim3(128, 4), 256, 0, stream>>>(x, Wth, Wtl, fhi, flo);
    sim_argmax_part<<<dim3(ROWS / 256, NQ), 256, 0, stream>>>(fhi, flo, chi, clo, pv, pi);
    merge_argmax<<<ROWS / 256, 256, 0, stream>>>(pv, pi, out);
}

// Round 6
// 284.967 us; speedup vs baseline: 1.8040x; 1.0530x over previous
//
#include <hip/hip_runtime.h>
#include <math.h>

#define BT 8192      // B*T
#define NDIM 512     // INPUT_DIM
#define NFREQ 257
#define DDIM 128     // VQ_DIM
#define NEMBED 8192
#define NQ 4         // codebook quarters
#define ROWS 32768   // BT*4 splits

typedef _Float16 half8 __attribute__((ext_vector_type(8)));
typedef _Float16 half2v __attribute__((ext_vector_type(2)));
typedef float f32x4 __attribute__((ext_vector_type(4)));

#define SCALE_DN 2.44140625e-4f   // 2^-12

// ---------------- K table: K_s[delta] = sum_{f: rm[f]==s} w_f cos(2*pi*f*delta/512) ----
__global__ __launch_bounds__(512) void build_K_kernel(const int* __restrict__ rm,
                                                      float* __restrict__ Kmat) {
    __shared__ float ctab[512];
    __shared__ int rms[NFREQ];
    int t = threadIdx.x;
    ctab[t] = cospif((float)t * (1.0f / 256.0f));   // cos(2*pi*t/512)
    if (t < NFREQ) rms[t] = rm[t];
    __syncthreads();
    float acc0 = 0.f, acc1 = 0.f, acc2 = 0.f, acc3 = 0.f;
    for (int f = 0; f < NFREQ; ++f) {
        float w = (f == 0 || f == 256) ? 1.0f : 2.0f;
        float c = w * ctab[(f * t) & 511];
        int s = rms[f];
        acc0 += (s == 0) ? c : 0.0f;
        acc1 += (s == 1) ? c : 0.0f;
        acc2 += (s == 2) ? c : 0.0f;
        acc3 += (s == 3) ? c : 0.0f;
    }
    const float sc = 1.0f / 512.0f;
    Kmat[0 * 512 + t] = acc0 * sc;
    Kmat[1 * 512 + t] = acc1 * sc;
    Kmat[2 * 512 + t] = acc2 * sc;
    Kmat[3 * 512 + t] = acc3 * sc;
}

// ------- W^T split: Wth/Wtl[c][k] = f16split(256 * sum_p proj[p][c&127] K_s[(p-k)&511]) -
__global__ __launch_bounds__(128) void build_W_split(const float* __restrict__ proj,
                                                     const float* __restrict__ Kmat,
                                                     _Float16* __restrict__ Wth,
                                                     _Float16* __restrict__ Wtl) {
    int nt = blockIdx.x, s = blockIdx.y, d = threadIdx.x;
    int n0 = nt * 8;
    __shared__ float Ks[512];
    for (int i = d; i < 512; i += 128) Ks[i] = Kmat[s * 512 + i];
    __syncthreads();
    float acc[8] = {};
    for (int p16 = 0; p16 < 512; p16 += 16) {
        float wv[23];
#pragma unroll
        for (int j2 = 0; j2 < 23; ++j2) wv[j2] = Ks[(p16 - n0 + j2 - 7) & 511];
#pragma unroll
        for (int j = 0; j < 16; ++j) {
            float xp = proj[(p16 + j) * DDIM + d];
#pragma unroll
            for (int i = 0; i < 8; ++i)
                acc[i] = fmaf(xp, wv[7 + j - i], acc[i]);
        }
    }
    size_t cbase = (size_t)(s * DDIM + d) * 512 + n0;
#pragma unroll
    for (int i = 0; i < 8; ++i) {
        float f = acc[i] * 256.0f;          // pre-scale: dodge f16 denormals (norm cancels)
        _Float16 h = (_Float16)f;
        Wth[cbase + i] = h;
        Wtl[cbase + i] = (_Float16)((f - (float)h) * 4096.0f);
    }
}

// ---- codebook: normalize + f16 hi/lo split, written in MFMA B-FRAGMENT order ----------
// image (halfs): tile*2048 + kt*512 + lg*128 + cr*8 + j, where code=tile*16+cr,
// k = kt*32 + lg*8 + j. Sim lane l then reads contiguous 16B at tile*2048+kt*512+l*8.
__global__ __launch_bounds__(256) void cbsplit_kernel(const float* __restrict__ cb,
                                                      _Float16* __restrict__ chi,
                                                      _Float16* __restrict__ clo) {
    int code = blockIdx.x * 4 + (threadIdx.x >> 6);
    int l = threadIdx.x & 63;                 // handles k = 2l, 2l+1
    float2 v = ((const float2*)(cb + (size_t)code * DDIM))[l];
    float ss = fmaf(v.x, v.x, v.y * v.y);
#pragma unroll
    for (int m = 32; m; m >>= 1) ss += __shfl_xor(ss, m);
    float r = 1.0f / sqrtf(ss);
    float a = v.x * r, b = v.y * r;
    _Float16 ha = (_Float16)a, hb = (_Float16)b;
    half2v hv = {ha, hb};
    half2v lv = {(_Float16)((a - (float)ha) * 4096.0f), (_Float16)((b - (float)hb) * 4096.0f)};
    int cr = code & 15, tile = code >> 4;
    int kt = l >> 4, lg = (l >> 2) & 3, j = 2 * (l & 3);
    size_t addr = (size_t)tile * 2048 + kt * 512 + lg * 128 + cr * 8 + j;
    *(half2v*)(chi + addr) = hv;
    *(half2v*)(clo + addr) = lv;
}

// ---------------- fused feat: feat = x @ W (f16x3 MFMA), row-normalize, split hi/lo -----
__global__ __launch_bounds__(256) void fused_feat(const float* __restrict__ x,
                                                  const _Float16* __restrict__ Wth,
                                                  const _Float16* __restrict__ Wtl,
                                                  _Float16* __restrict__ fhi,
                                                  _Float16* __restrict__ flo) {
    __shared__ __align__(16) char smem[59392];
    float* xs = (float*)smem;                       // [2][64][36] f32
    _Float16* Wh = (_Float16*)(smem + 18432);       // [2][128][40] f16
    _Float16* Wl = (_Float16*)(smem + 38912);       // [2][128][40] f16

    int t = threadIdx.x;
    int w = t >> 6, lr = t & 15, lg = (t >> 4) & 3;
    int row0 = blockIdx.x * 64;
    int sIdx = blockIdx.y;

    int xr_r = t >> 2, xr_c = (t & 3) * 8;
    int wcol = t >> 1, wh_h = t & 1;
    const float* xsrc = x + (size_t)(row0 + xr_r) * NDIM + xr_c;
    const _Float16* whsrc = Wth + (size_t)(sIdx * 128 + wcol) * 512 + wh_h * 16;
    const _Float16* wlsrc = Wtl + (size_t)(sIdx * 128 + wcol) * 512 + wh_h * 16;

    f32x4 c0[8], c1[8];
#pragma unroll
    for (int i = 0; i < 8; ++i) { c0[i] = (f32x4){0.f,0.f,0.f,0.f}; c1[i] = c0[i]; }

    {
        float4 a0 = *(const float4*)(xsrc);
        float4 a1 = *(const float4*)(xsrc + 4);
        *(float4*)&xs[xr_r * 36 + xr_c] = a0;
        *(float4*)&xs[xr_r * 36 + xr_c + 4] = a1;
        half8 h0 = *(const half8*)(whsrc);
        half8 h1 = *(const half8*)(whsrc + 8);
        half8 l0 = *(const half8*)(wlsrc);
        half8 l1 = *(const half8*)(wlsrc + 8);
        *(half8*)&Wh[wcol * 40 + wh_h * 16] = h0;
        *(half8*)&Wh[wcol * 40 + wh_h * 16 + 8] = h1;
        *(half8*)&Wl[wcol * 40 + wh_h * 16] = l0;
        *(half8*)&Wl[wcol * 40 + wh_h * 16 + 8] = l1;
    }

    for (int it = 0; it < 16; ++it) {
        __syncthreads();
        int buf = it & 1;
        float4 nx0, nx1; half8 nh0, nh1, nl0, nl1;
        bool have = (it + 1) < 16;
        if (have) {
            int k0 = (it + 1) * 32;
            nx0 = *(const float4*)(xsrc + k0);
            nx1 = *(const float4*)(xsrc + k0 + 4);
            nh0 = *(const half8*)(whsrc + k0);
            nh1 = *(const half8*)(whsrc + k0 + 8);
            nl0 = *(const half8*)(wlsrc + k0);
            nl1 = *(const half8*)(wlsrc + k0 + 8);
        }
        const float* xb = xs + buf * 2304;
        float4 f0 = *(const float4*)&xb[(w * 16 + lr) * 36 + lg * 8];
        float4 f1 = *(const float4*)&xb[(w * 16 + lr) * 36 + lg * 8 + 4];
        float fv[8] = {f0.x, f0.y, f0.z, f0.w, f1.x, f1.y, f1.z, f1.w};
        half8 ah, al;
#pragma unroll
        for (int j = 0; j < 8; ++j) {
            _Float16 h = (_Float16)fv[j];
            ah[j] = h;
            al[j] = (_Float16)((fv[j] - (float)h) * 4096.0f);
        }
        const _Float16* whb = Wh + buf * 5120;
        const _Float16* wlb = Wl + buf * 5120;
#pragma unroll
        for (int set = 0; set < 8; ++set) {
            int bcol = set * 16 + lr;
            half8 bh = *(const half8*)&whb[bcol * 40 + lg * 8];
            half8 bl = *(const half8*)&wlb[bcol * 40 + lg * 8];
            c0[set] = __builtin_amdgcn_mfma_f32_16x16x32_f16(ah, bh, c0[set], 0, 0, 0);
            c1[set] = __builtin_amdgcn_mfma_f32_16x16x32_f16(ah, bl, c1[set], 0, 0, 0);
            c1[set] = __builtin_amdgcn_mfma_f32_16x16x32_f16(al, bh, c1[set], 0, 0, 0);
        }
        __syncthreads();
        if (have) {
            *(float4*)&xs[(buf ^ 1) * 2304 + xr_r * 36 + xr_c] = nx0;
            *(float4*)&xs[(buf ^ 1) * 2304 + xr_r * 36 + xr_c + 4] = nx1;
            _Float16* dh = Wh + (buf ^ 1) * 5120 + wcol * 40 + wh_h * 16;
            _Float16* dl = Wl + (buf ^ 1) * 5120 + wcol * 40 + wh_h * 16;
            *(half8*)(dh) = nh0; *(half8*)(dh + 8) = nh1;
            *(half8*)(dl) = nl0; *(half8*)(dl + 8) = nl1;
        }
    }
    __syncthreads();

    float* few = (float*)smem + w * 2112;           // [16][132]
    float ss[4] = {0.f, 0.f, 0.f, 0.f};
    float vv[8][4];
#pragma unroll
    for (int set = 0; set < 8; ++set)
#pragma unroll
        for (int r = 0; r < 4; ++r) {
            float v = fmaf(c1[set][r], SCALE_DN, c0[set][r]);
            vv[set][r] = v;
            ss[r] = fmaf(v, v, ss[r]);
        }
#pragma unroll
    for (int r = 0; r < 4; ++r) {
#pragma unroll
        for (int m = 1; m < 16; m <<= 1) ss[r] += __shfl_xor(ss[r], m);
    }
    float rn[4];
#pragma unroll
    for (int r = 0; r < 4; ++r) rn[r] = rsqrtf(ss[r]);
#pragma unroll
    for (int set = 0; set < 8; ++set)
#pragma unroll
        for (int r = 0; r < 4; ++r)
            few[(4 * lg + r) * 132 + set * 16 + lr] = vv[set][r] * rn[r];
    __syncthreads();
    int l = t & 63;
    int rr = l >> 2, q = l & 3;
    size_t btg = (size_t)(row0 + w * 16 + rr);
    size_t dst = (btg * 4 + sIdx) * DDIM + q * 32;
#pragma unroll
    for (int g = 0; g < 4; ++g) {
        half8 oh, ol;
#pragma unroll
        for (int j = 0; j < 8; ++j) {
            float f = few[rr * 132 + q * 32 + g * 8 + j];
            _Float16 h = (_Float16)f;
            oh[j] = h;
            ol[j] = (_Float16)((f - (float)h) * 4096.0f);
        }
        *(half8*)(fhi + dst + g * 8) = oh;
        *(half8*)(flo + dst + g * 8) = ol;
    }
}

// ---------------- sim + argmax partial: 256 feat rows x 2048-code quarter ---------------
// grid (128 row-tiles, 4 quarters); 4 waves x 64 rows; B fragments loaded global->reg
// from the fragment-ordered codebook image (coalesced dwordx4). No LDS in main loop.
__global__ __launch_bounds__(256, 2) void sim_argmax_part(const _Float16* __restrict__ fhi,
                                                          const _Float16* __restrict__ flo,
                                                          const _Float16* __restrict__ chi,
                                                          const _Float16* __restrict__ clo,
                                                          float* __restrict__ pv,
                                                          int* __restrict__ pi) {
    __shared__ float redv[256][17];
    __shared__ int   redi[256][17];

    int t = threadIdx.x;
    int w = t >> 6, l = t & 63, lr = t & 15, lg = (t >> 4) & 3;
    int row0 = blockIdx.x * 256;
    int q = blockIdx.y;

    // A fragments (4 sets x 4 kt), resident whole kernel: 128 VGPR
    half8 ahi[4][4], alo[4][4];
#pragma unroll
    for (int s = 0; s < 4; ++s)
#pragma unroll
        for (int kt = 0; kt < 4; ++kt) {
            size_t off = (size_t)(row0 + w * 64 + s * 16 + lr) * DDIM + kt * 32 + lg * 8;
            ahi[s][kt] = *(const half8*)(fhi + off);
            alo[s][kt] = *(const half8*)(flo + off);
        }

    // fragment-order image: half8 index = tile*256 + kt*64 + lane
    const half8* cf = (const half8*)chi;
    const half8* cv = (const half8*)clo;
    size_t base = (size_t)(q * (NEMBED / NQ / 16)) * 256 + l;   // quarter tile base + lane

    half8 bh[4], bl[4];
#pragma unroll
    for (int kt = 0; kt < 4; ++kt) {
        bh[kt] = cf[base + kt * 64];
        bl[kt] = cv[base + kt * 64];
    }

    float best[4][4];
    int btile[4][4];
#pragma unroll
    for (int s = 0; s < 4; ++s)
#pragma unroll
        for (int r = 0; r < 4; ++r) { best[s][r] = -1e30f; btile[s][r] = 0; }

    const int NT = NEMBED / (16 * NQ);   // 128 tiles per quarter
    for (int it = 0; it < NT; ++it) {
        f32x4 a0[4], a1[4];
#pragma unroll
        for (int s = 0; s < 4; ++s) { a0[s] = (f32x4){0.f,0.f,0.f,0.f}; a1[s] = a0[s]; }
        size_t nb = base + (size_t)(it + 1) * 256;
        bool have = (it + 1) < NT;
#pragma unroll
        for (int kt = 0; kt < 4; ++kt) {
#pragma unroll
            for (int s = 0; s < 4; ++s) {
                a0[s] = __builtin_amdgcn_mfma_f32_16x16x32_f16(ahi[s][kt], bh[kt], a0[s], 0, 0, 0);
                a1[s] = __builtin_amdgcn_mfma_f32_16x16x32_f16(ahi[s][kt], bl[kt], a1[s], 0, 0, 0);
                a1[s] = __builtin_amdgcn_mfma_f32_16x16x32_f16(alo[s][kt], bh[kt], a1[s], 0, 0, 0);
            }
            if (have) {   // WAR-safe: MFMAs above already read bh/bl at issue
                bh[kt] = cf[nb + kt * 64];
                bl[kt] = cv[nb + kt * 64];
            }
        }
#pragma unroll
        for (int s = 0; s < 4; ++s)
#pragma unroll
            for (int r = 0; r < 4; ++r) {
                float v = fmaf(a1[s][r], SCALE_DN, a0[s][r]);
                if (v > best[s][r]) { best[s][r] = v; btile[s][r] = it; }
            }
    }

#pragma unroll
    for (int s = 0; s < 4; ++s)
#pragma unroll
        for (int r = 0; r < 4; ++r) {
            int row = w * 64 + s * 16 + 4 * lg + r;
            redv[row][lr] = best[s][r];
            redi[row][lr] = q * (NEMBED / NQ) + btile[s][r] * 16 + lr;
        }
    __syncthreads();
    {
        float bv = redv[t][0]; int bi = redi[t][0];
#pragma unroll
        for (int c = 1; c < 16; ++c) {
            float v = redv[t][c]; int ii = redi[t][c];
            if (v > bv || (v == bv && ii < bi)) { bv = v; bi = ii; }
        }
        pv[(size_t)q * ROWS + row0 + t] = bv;
        pi[(size_t)q * ROWS + row0 + t] = bi;
    }
}

// ---------------- merge 4 quarter-candidates per row ------------------------------------
__global__ __launch_bounds__(256) void merge_argmax(const float* __restrict__ pv,
                                                    const int* __restrict__ pi,
                                                    int* __restrict__ out) {
    int row = blockIdx.x * 256 + threadIdx.x;
    float bv = pv[row]; int bi = pi[row];
#pragma unroll
    for (int q = 1; q < NQ; ++q) {
        float v = pv[(size_t)q * ROWS + row];
        if (v > bv) { bv = v; bi = pi[(size_t)q * ROWS + row]; }   // ties -> lower q wins
    }
    out[row] = bi;
}

extern "C" void kernel_launch(void* const* d_in, const int* in_sizes, int n_in,
                              void* d_out, int out_size, void* d_ws, size_t ws_size,
                              hipStream_t stream) {
    const float* x    = (const float*)d_in[0];   // [32,256,512]
    const float* proj = (const float*)d_in[1];   // [512,128]
    const float* cb   = (const float*)d_in[2];   // [1,8192,128]
    const int*   rm   = (const int*)d_in[3];     // [257]
    int* out = (int*)d_out;                      // [32,256,4,1] int32

    char* wsb = (char*)d_ws;
    float*    Kmat = (float*)(wsb + 0);              // 8 KB
    _Float16* Wth  = (_Float16*)(wsb + 8192);        // 512 KB
    _Float16* Wtl  = (_Float16*)(wsb + 532480);      // 512 KB
    _Float16* chi  = (_Float16*)(wsb + 1056768);     // 2 MB (B-fragment order)
    _Float16* clo  = (_Float16*)(wsb + 3153920);     // 2 MB
    _Float16* fhi  = (_Float16*)(wsb + 5251072);     // 8 MB
    _Float16* flo  = (_Float16*)(wsb + 13639680);    // 8 MB
    float*    pv   = (float*)(wsb + 22028288);       // 512 KB
    int*      pi   = (int*)(wsb + 22552576);         // 512 KB (end ~23 MB)

    build_K_kernel<<<1, 512, 0, stream>>>(rm, Kmat);
    build_W_split<<<dim3(64, 4), 128, 0, stream>>>(proj, Kmat, Wth, Wtl);
    cbsplit_kernel<<<NEMBED / 4, 256, 0, stream>>>(cb, chi, clo);
    fused_feat<<<dim3(128, 4), 256, 0, stream>>>(x, Wth, Wtl, fhi, flo);
    sim_argmax_part<<<dim3(ROWS / 256, NQ), 256, 0, stream>>>(fhi, flo, chi, clo, pv, pi);
    merge_argmax<<<ROWS / 256, 256, 0, stream>>>(pv, pi, out);
}